// Round 1
// baseline (617.144 us; speedup 1.0000x reference)
//
// AttLayer block-local attention, MI355X gfx950.
// R1: correctness-first structured implementation.
//   All matmuls share one MFMA GEMM template: C[M][N] = A[M][K] @ Bt[N][K]^T,
//   A,Bt row-major bf16, 128x128 tile, BK=32, 4 waves, global_load_lds(16B),
//   m97-style 2-barrier K-loop. Halo/padding handled by redirecting OOB lanes
//   to a zeroed guard page (MFMA sees exact zeros). Softmax in fp32, faithful
//   to reference (log(mask+1e-9) additive, then *mask).
// Workspace layout (272 MiB): xT | Wqk | Wv | Wo | qkT | v | S | P | guard.
//   attT aliases xT (xT dead after the two projection GEMMs).

#include <hip/hip_runtime.h>
#include <hip/hip_bf16.h>

typedef __attribute__((ext_vector_type(4))) float f32x4;
typedef __attribute__((ext_vector_type(8))) __bf16 bf16x8;

#define DEVINL static __device__ __forceinline__

DEVINL unsigned short f2bf(float f) {  // RTNE float->bf16
  union { float f; unsigned u; } x; x.f = f;
  return (unsigned short)((x.u + 0x7FFFu + ((x.u >> 16) & 1u)) >> 16);
}

DEVINL void gload16(const void* g, void* l) {
  __builtin_amdgcn_global_load_lds((const __attribute__((address_space(1))) void*)g,
                                   (__attribute__((address_space(3))) void*)l,
                                   16, 0, 0);
}

// ---------------------------------------------------------------- transpose x
// x1 [2048][16384] f32 -> xT [16384][2048] bf16 (RTNE)
__global__ __launch_bounds__(256) void transpose_x_k(const float* __restrict__ x,
                                                     unsigned short* __restrict__ xT) {
  __shared__ float tile[32][33];
  const int bx = blockIdx.x;  // L/32 = 512
  const int by = blockIdx.y;  // C/32 = 64
  const int tx = threadIdx.x; // 32
  const int ty = threadIdx.y; // 8
#pragma unroll
  for (int i = 0; i < 4; ++i) {
    int c = by * 32 + ty + i * 8;
    tile[ty + i * 8][tx] = x[(long)c * 16384 + bx * 32 + tx];
  }
  __syncthreads();
#pragma unroll
  for (int i = 0; i < 4; ++i) {
    int l = bx * 32 + ty + i * 8;
    xT[(long)l * 2048 + by * 32 + tx] = f2bf(tile[tx][ty + i * 8]);
  }
}

// ------------------------------------------------------------ weight convert
// Wqk[2048][2048] = concat(wq, wk); Wv[1024][2048]; Wo[2048][1024]  (bf16)
__global__ __launch_bounds__(256) void conv_w_k(const float* __restrict__ wq,
                                                const float* __restrict__ wk,
                                                const float* __restrict__ wv,
                                                const float* __restrict__ wo,
                                                unsigned short* __restrict__ Wqk,
                                                unsigned short* __restrict__ Wv,
                                                unsigned short* __restrict__ Wo) {
  long i = (long)blockIdx.x * 256 + threadIdx.x;   // 0..8388607
  if (i < 4194304) {
    float s = (i < 2097152) ? wq[i] : wk[i - 2097152];
    Wqk[i] = f2bf(s);
  } else if (i < 6291456) {
    Wv[i - 4194304] = f2bf(wv[i - 4194304]);
  } else {
    Wo[i - 6291456] = f2bf(wo[i - 6291456]);
  }
}

// ------------------------------------------------------------------ GEMM core
enum { EPI_QK = 0, EPI_V = 1, EPI_S = 2, EPI_PV = 3, EPI_OUT = 4 };

struct GArgs {
  const unsigned short* A;   // bf16 [M][lda] (+ z*aBatch)
  const unsigned short* Bt;  // bf16, row grow = btRow0 + z*btRow0Step + Nbase + r
  void* C;
  const float* bias;   // EPI-specific
  const float* bias2;  // EPI_QK: bk
  const float* mask;   // EPI_OUT
  const unsigned short* guard;  // >= 1KB of zeros
  int lda, ldb, ldc, K;
  int aBatch, cBatch;                  // element strides per blockIdx.z
  int btRow0, btRow0Step, btRowLim;    // valid iff (unsigned)grow < btRowLim
  int btK0, btK0Step, btKLim;          // valid iff (unsigned)gk  < btKLim
};

template <int EPI>
__global__ __launch_bounds__(256) void gemm_k(GArgs g) {
  __shared__ unsigned short ldsA[128 * 32];
  __shared__ unsigned short ldsB[128 * 32];
  const int t = threadIdx.x;
  const int Nbase = blockIdx.x * 128;
  const int Mbase = blockIdx.y * 128;
  const int z = blockIdx.z;

  const unsigned short* Ab = g.A + (long)z * g.aBatch + (long)Mbase * g.lda;
  const int bRowBase = g.btRow0 + z * g.btRow0Step + Nbase;
  const int bK0 = g.btK0 + z * g.btK0Step;

  const int r4 = t >> 2;            // staging row within 64-row half
  const int cb = (t & 3) << 4;      // byte offset within 64B row chunk
  const int kce = (t & 3) << 3;     // element offset within 32-elem K chunk
  const int NK = g.K >> 5;

  const int wave = t >> 6;
  const int lane = t & 63;
  const int wm = (wave >> 1) << 6;  // wave 64x64 sub-tile
  const int wn = (wave & 1) << 6;
  const int fr = lane & 15;
  const int fg = lane >> 4;

  f32x4 acc[4][4];
#pragma unroll
  for (int i = 0; i < 4; ++i)
#pragma unroll
    for (int j = 0; j < 4; ++j) acc[i][j] = f32x4{0.f, 0.f, 0.f, 0.f};

  auto stageA = [&](int k0) {
#pragma unroll
    for (int p = 0; p < 2; ++p) {
      const char* gp = (const char*)(Ab + (long)(p * 64 + r4) * g.lda + k0) + cb;
      char* lp = (char*)ldsA + p * 4096 + (t << 4);
      gload16(gp, lp);
    }
  };
  auto stageB = [&](int k0) {
#pragma unroll
    for (int p = 0; p < 2; ++p) {
      int row = p * 64 + r4;
      int grow = bRowBase + row;
      int gk = bK0 + k0 + kce;
      const char* gp;
      if ((unsigned)grow < (unsigned)g.btRowLim && (unsigned)gk < (unsigned)g.btKLim)
        gp = (const char*)(g.Bt + (long)grow * g.ldb + gk);
      else
        gp = (const char*)g.guard + ((t & 63) << 4);  // zeros
      char* lp = (char*)ldsB + p * 4096 + (t << 4);
      gload16(gp, lp);
    }
  };

  stageA(0);
  stageB(0);
  for (int ks = 0; ks < NK; ++ks) {
    __syncthreads();  // drains vmcnt: staged tile visible
    bf16x8 af[4], bfr[4];
#pragma unroll
    for (int i = 0; i < 4; ++i) {
      af[i]  = *(const bf16x8*)(ldsA + ((wm + i * 16 + fr) * 32 + fg * 8));
      bfr[i] = *(const bf16x8*)(ldsB + ((wn + i * 16 + fr) * 32 + fg * 8));
    }
    __syncthreads();  // all waves done reading LDS
    if (ks + 1 < NK) { stageA((ks + 1) << 5); stageB((ks + 1) << 5); }
#pragma unroll
    for (int i = 0; i < 4; ++i)
#pragma unroll
      for (int j = 0; j < 4; ++j)
        acc[i][j] = __builtin_amdgcn_mfma_f32_16x16x32_bf16(af[i], bfr[j], acc[i][j], 0, 0, 0);
  }

  // epilogue: D row=(lane>>4)*4+r, col=lane&15 (measured layout)
#pragma unroll
  for (int i = 0; i < 4; ++i)
#pragma unroll
    for (int j = 0; j < 4; ++j)
#pragma unroll
      for (int r = 0; r < 4; ++r) {
        const int row = Mbase + wm + i * 16 + fg * 4 + r;
        const int col = Nbase + wn + j * 16 + fr;
        float val = acc[i][j][r];
        const long off = (long)z * g.cBatch + (long)row * g.ldc + col;
        if (EPI == EPI_QK) {
          // q rows pre-scaled by 1/sqrt(1024); biases folded in fp32
          val = (col < 1024) ? (val + g.bias[col]) * 0.03125f
                             : (val + g.bias2[col - 1024]);
          ((unsigned short*)g.C)[off] = f2bf(val);
        } else if (EPI == EPI_V) {
          val += g.bias[row];
          ((unsigned short*)g.C)[off] = f2bf(val);
        } else if (EPI == EPI_S) {
          ((float*)g.C)[off] = val;
        } else if (EPI == EPI_PV) {
          val = fmaxf(val, 0.f);  // relu before bf16
          ((unsigned short*)g.C)[off] = f2bf(val);
        } else {  // EPI_OUT
          val = (val + g.bias[row]) * g.mask[col];
          ((float*)g.C)[off] = val;
        }
      }
}

// ------------------------------------------------------------------- softmax
// S [16384][1024] f32 -> P [16384][1024] bf16, faithful to reference:
// logit = s + log(fm + 1e-9); p = exp(logit - max)/sum * fm
__global__ __launch_bounds__(256) void softmax_k(const float* __restrict__ S,
                                                 const float* __restrict__ mask,
                                                 unsigned short* __restrict__ P) {
  const int row = blockIdx.x;      // n*512 + l
  const int n = row >> 9;
  const float* s = S + (long)row * 1024;
  unsigned short* p = P + (long)row * 1024;
  const int t = threadIdx.x;

  float logit[4], fm[4];
  float lmax = -3.0e38f;
#pragma unroll
  for (int i = 0; i < 4; ++i) {
    int m = i * 256 + t;
    int pos = (n << 9) + m - 256;   // position in unpadded L
    float f = (((unsigned)pos < 16384u) && (m != 1023)) ? mask[pos] : 0.f;
    float lg = s[m] + logf(f + 1e-9f);
    fm[i] = f; logit[i] = lg;
    lmax = fmaxf(lmax, lg);
  }
#pragma unroll
  for (int o = 32; o; o >>= 1) lmax = fmaxf(lmax, __shfl_xor(lmax, o, 64));
  __shared__ float red[8];
  const int wv_ = t >> 6, ln = t & 63;
  if (ln == 0) red[wv_] = lmax;
  __syncthreads();
  const float gmax = fmaxf(fmaxf(red[0], red[1]), fmaxf(red[2], red[3]));

  float e[4], lsum = 0.f;
#pragma unroll
  for (int i = 0; i < 4; ++i) { e[i] = expf(logit[i] - gmax); lsum += e[i]; }
#pragma unroll
  for (int o = 32; o; o >>= 1) lsum += __shfl_xor(lsum, o, 64);
  __syncthreads();
  if (ln == 0) red[4 + wv_] = lsum;
  __syncthreads();
  const float inv = 1.f / ((red[4] + red[5]) + (red[6] + red[7]));
#pragma unroll
  for (int i = 0; i < 4; ++i) {
    int m = i * 256 + t;
    p[m] = f2bf(e[i] * inv * fm[i]);
  }
}

// -------------------------------------------------------------------- launch
extern "C" void kernel_launch(void* const* d_in, const int* in_sizes, int n_in,
                              void* d_out, int out_size, void* d_ws, size_t ws_size,
                              hipStream_t stream) {
  const float* x1 = (const float*)d_in[0];
  // d_in[1] = x2 (unused by reference)
  const float* mask = (const float*)d_in[2];
  const float* wq = (const float*)d_in[3];
  const float* bq = (const float*)d_in[4];
  const float* wk = (const float*)d_in[5];
  const float* bk = (const float*)d_in[6];
  const float* wv = (const float*)d_in[7];
  const float* bv = (const float*)d_in[8];
  const float* wo = (const float*)d_in[9];
  const float* bo = (const float*)d_in[10];

  char* ws = (char*)d_ws;
  unsigned short* xT   = (unsigned short*)(ws);                  // 64 MiB
  unsigned short* attT = xT;                                     // alias: xT dead after projections
  unsigned short* Wqk  = (unsigned short*)(ws + 67108864);       // 8 MiB
  unsigned short* Wv   = (unsigned short*)(ws + 75497472);       // 4 MiB
  unsigned short* Wo   = (unsigned short*)(ws + 79691776);       // 4 MiB
  unsigned short* qkT  = (unsigned short*)(ws + 83886080);       // 64 MiB
  unsigned short* vbuf = (unsigned short*)(ws + 150994944);      // 32 MiB
  float*          Sbuf = (float*)(ws + 184549376);               // 64 MiB
  unsigned short* P    = (unsigned short*)(ws + 251658240);      // 32 MiB
  unsigned short* guard= (unsigned short*)(ws + 285212672);      // 4 KiB zeros

  hipMemsetAsync(guard, 0, 4096, stream);

  transpose_x_k<<<dim3(512, 64), dim3(32, 8), 0, stream>>>(x1, xT);
  conv_w_k<<<dim3(32768), dim3(256), 0, stream>>>(wq, wk, wv, wo, Wqk, Wv, Wo);

  const int BIG = 0x40000000;
  // 1) qkT[16384][2048] = xT @ Wqk^T  (+bias, q-part scaled 1/32)
  {
    GArgs a{};
    a.A = xT; a.Bt = Wqk; a.C = qkT;
    a.bias = bq; a.bias2 = bk; a.mask = nullptr; a.guard = guard;
    a.lda = 2048; a.ldb = 2048; a.ldc = 2048; a.K = 2048;
    a.aBatch = 0; a.cBatch = 0;
    a.btRow0 = 0; a.btRow0Step = 0; a.btRowLim = BIG;
    a.btK0 = 0; a.btK0Step = 0; a.btKLim = BIG;
    gemm_k<EPI_QK><<<dim3(16, 128, 1), dim3(256), 0, stream>>>(a);
  }
  // 2) v[1024][16384] = Wv @ x  (= Wv[M][K] @ xT[N][K]^T) + bv
  {
    GArgs a{};
    a.A = Wv; a.Bt = xT; a.C = vbuf;
    a.bias = bv; a.bias2 = nullptr; a.mask = nullptr; a.guard = guard;
    a.lda = 2048; a.ldb = 2048; a.ldc = 16384; a.K = 2048;
    a.aBatch = 0; a.cBatch = 0;
    a.btRow0 = 0; a.btRow0Step = 0; a.btRowLim = BIG;
    a.btK0 = 0; a.btK0Step = 0; a.btKLim = BIG;
    gemm_k<EPI_V><<<dim3(128, 8, 1), dim3(256), 0, stream>>>(a);
  }
  // 3) S[n][512][1024] = Qb @ Kb^T  (halo rows via guard)
  {
    GArgs a{};
    a.A = qkT; a.Bt = qkT; a.C = Sbuf;
    a.bias = nullptr; a.bias2 = nullptr; a.mask = nullptr; a.guard = guard;
    a.lda = 2048; a.ldb = 2048; a.ldc = 1024; a.K = 1024;
    a.aBatch = 512 * 2048; a.cBatch = 512 * 1024;
    a.btRow0 = -256; a.btRow0Step = 512; a.btRowLim = 16384;
    a.btK0 = 1024; a.btK0Step = 0; a.btKLim = BIG;  // k part of qkT rows
    gemm_k<EPI_S><<<dim3(8, 4, 32), dim3(256), 0, stream>>>(a);
  }
  // 4) softmax rows -> P bf16 (normalized, masked)
  softmax_k<<<dim3(16384), dim3(256), 0, stream>>>(Sbuf, mask, P);
  // 5) attT[n][512 l][1024 c] = relu(P @ Vb^T)   (halo cols via guard)
  {
    GArgs a{};
    a.A = P; a.Bt = vbuf; a.C = attT;
    a.bias = nullptr; a.bias2 = nullptr; a.mask = nullptr; a.guard = guard;
    a.lda = 1024; a.ldb = 16384; a.ldc = 1024; a.K = 1024;
    a.aBatch = 512 * 1024; a.cBatch = 512 * 1024;
    a.btRow0 = 0; a.btRow0Step = 0; a.btRowLim = BIG;
    a.btK0 = -256; a.btK0Step = 512; a.btKLim = 16384;
    gemm_k<EPI_PV><<<dim3(8, 4, 32), dim3(256), 0, stream>>>(a);
  }
  // 6) out[2048][16384] = (Wo @ attT^T + bo) * mask   (fp32 to d_out)
  {
    GArgs a{};
    a.A = Wo; a.Bt = attT; a.C = d_out;
    a.bias = bo; a.bias2 = nullptr; a.mask = mask; a.guard = guard;
    a.lda = 1024; a.ldb = 1024; a.ldc = 16384; a.K = 1024;
    a.aBatch = 0; a.cBatch = 0;
    a.btRow0 = 0; a.btRow0Step = 0; a.btRowLim = BIG;
    a.btK0 = 0; a.btK0Step = 0; a.btKLim = BIG;
    gemm_k<EPI_OUT><<<dim3(128, 16, 1), dim3(256), 0, stream>>>(a);
  }
  (void)in_sizes; (void)n_in; (void)out_size; (void)ws_size;
}

// Round 2
// 502.644 us; speedup vs baseline: 1.2278x; 1.2278x over previous
//
// AttLayer block-local attention, MI355X gfx950.
// R2: all five GEMMs ported to the 256x256 8-phase template (T2+T3/T4+T5):
//   - 8 waves (2Mx4N), per-wave 128x64 output, BK=64, LDS 128 KiB double-buffer
//   - XOR swizzle: read slot = (kk*4+fg) ^ (row&7); source pre-swizzled,
//     global_load_lds destination linear (both-sides-or-neither rule)
//   - counted s_waitcnt vmcnt(6) at phases 3/7 only; raw s_barrier (asm, no
//     drain); vmcnt(0) once after the K-loop
//   - s_setprio(1) around each 16-MFMA cluster
//   Phase->stage-unit map verified: every stage targets a region whose last
//   reader phase is strictly earlier (write-after-read safe), and every
//   consumer phase is covered by a prior vmcnt(6)+barrier (read-after-write).
// Workspace: xT | Wqk | Wv | Wo | qkT | v | S | P | guard (attT aliases xT).

#include <hip/hip_runtime.h>
#include <hip/hip_bf16.h>

typedef __attribute__((ext_vector_type(4))) float f32x4;
typedef __attribute__((ext_vector_type(8))) __bf16 bf16x8;

#define DEVINL static __device__ __forceinline__

DEVINL unsigned short f2bf(float f) {  // RTNE float->bf16
  union { float f; unsigned u; } x; x.f = f;
  return (unsigned short)((x.u + 0x7FFFu + ((x.u >> 16) & 1u)) >> 16);
}

DEVINL void gload16(const void* g, void* l) {
  __builtin_amdgcn_global_load_lds((const __attribute__((address_space(1))) void*)g,
                                   (__attribute__((address_space(3))) void*)l,
                                   16, 0, 0);
}

#define SBAR()  asm volatile("s_barrier" ::: "memory")
#define LGKM0() asm volatile("s_waitcnt lgkmcnt(0)" ::: "memory")
#define VM(n)   asm volatile("s_waitcnt vmcnt(" #n ")" ::: "memory")

// ---------------------------------------------------------------- transpose x
// x1 [2048][16384] f32 -> xT [16384][2048] bf16 (RTNE)
__global__ __launch_bounds__(256) void transpose_x_k(const float* __restrict__ x,
                                                     unsigned short* __restrict__ xT) {
  __shared__ float tile[32][33];
  const int bx = blockIdx.x;  // L/32 = 512
  const int by = blockIdx.y;  // C/32 = 64
  const int tx = threadIdx.x; // 32
  const int ty = threadIdx.y; // 8
#pragma unroll
  for (int i = 0; i < 4; ++i) {
    int c = by * 32 + ty + i * 8;
    tile[ty + i * 8][tx] = x[(long)c * 16384 + bx * 32 + tx];
  }
  __syncthreads();
#pragma unroll
  for (int i = 0; i < 4; ++i) {
    int l = bx * 32 + ty + i * 8;
    xT[(long)l * 2048 + by * 32 + tx] = f2bf(tile[tx][ty + i * 8]);
  }
}

// ------------------------------------------------------------ weight convert
__global__ __launch_bounds__(256) void conv_w_k(const float* __restrict__ wq,
                                                const float* __restrict__ wk,
                                                const float* __restrict__ wv,
                                                const float* __restrict__ wo,
                                                unsigned short* __restrict__ Wqk,
                                                unsigned short* __restrict__ Wv,
                                                unsigned short* __restrict__ Wo) {
  long i = (long)blockIdx.x * 256 + threadIdx.x;   // 0..8388607
  if (i < 4194304) {
    float s = (i < 2097152) ? wq[i] : wk[i - 2097152];
    Wqk[i] = f2bf(s);
  } else if (i < 6291456) {
    Wv[i - 4194304] = f2bf(wv[i - 4194304]);
  } else {
    Wo[i - 6291456] = f2bf(wo[i - 6291456]);
  }
}

// ------------------------------------------------------------------ GEMM core
enum { EPI_QK = 0, EPI_V = 1, EPI_S = 2, EPI_PV = 3, EPI_OUT = 4 };

struct GArgs {
  const unsigned short* A;   // bf16 [M][LDA] (+ z*aBatch)
  const unsigned short* Bt;  // bf16, row grow = btRow0 + z*btRow0Step + Nbase + r
  void* C;
  const float* bias;
  const float* bias2;
  const float* mask;
  const unsigned short* guard;  // >= 1KB zeros
  int aBatch, cBatch;
  int btRow0, btRow0Step, btRowLim;
  int btK0, btK0Step, btKLim;
};

// 256x256 tile, BK=64, 8 waves (2M x 4N), per-wave 128x64, 8-phase pipeline.
template <int EPI, int LDA, int LDB, int LDC, int KK>
__global__ __launch_bounds__(512, 2) void gemm8_k(GArgs g) {
  constexpr int NK = KK >> 6;   // K-tiles of 64
  constexpr int NT = NK >> 1;   // loop iterations (2 K-tiles each)
  __shared__ char lds[131072];  // buf0.A | buf0.B | buf1.A | buf1.B (32K each)

  const int t = threadIdx.x;
  const int l = t & 63;
  const int w = t >> 6;
  const int Nbase = blockIdx.x << 8;
  const int Mbase = blockIdx.y << 8;
  const int z = blockIdx.z;

  const int wr = w >> 2;   // 0..1 (M half)
  const int wc = w & 3;    // 0..3 (N quarter)
  const int fr = l & 15;
  const int fg = l >> 4;

  const unsigned short* Ab = g.A + (long)z * g.aBatch + (long)Mbase * LDA;
  const int bRowBase = g.btRow0 + z * g.btRow0Step + Nbase;
  const int bK0 = g.btK0 + z * g.btK0Step;

  const int rr = t >> 3;     // staging row-within-unit-chunk: 0..63
  const int cb8s = t & 7;    // staging 16B slot within row

  // stage one 16 KiB unit (2 x global_load_lds per wave) of K-tile kt.
  // unit 0: A rows 0-63 & 128-191   unit 3: A rows 64-127 & 192-255
  // unit 1: B rows {0-31,64-95} & {128-159,192-223}
  // unit 2: B rows {32-63,96-127} & {160-191,224-255}
  auto stage = [&](int bufSel, int unit, int kt) {
    const int k0 = (kt & (NK - 1)) << 6;
    const bool isA = (unit == 0) || (unit == 3);
#pragma unroll
    for (int gph = 0; gph < 2; ++gph) {
      int row;
      if (isA) row = (unit == 0 ? 0 : 64) + (gph << 7) + rr;
      else     row = (unit == 1 ? 0 : 32) + (gph << 7) + (rr & 31) + ((rr >> 5) << 6);
      const int cbL = cb8s ^ (row & 7);        // pre-swizzled source slot
      const int gk = k0 + (cbL << 3);
      char* lp = lds + (bufSel << 16) + (isA ? 0 : 32768) + row * 128 + (cb8s << 4);
      const char* gp;
      if (isA) {
        gp = (const char*)(Ab + (long)row * LDA + gk);
      } else {
        const int grow = bRowBase + row;
        const int gkk = bK0 + gk;
        if ((unsigned)grow < (unsigned)g.btRowLim && (unsigned)gkk < (unsigned)g.btKLim)
          gp = (const char*)(g.Bt + (long)grow * LDB + gkk);
        else
          gp = (const char*)g.guard + (l << 4);  // zeros
      }
      gload16(gp, lp);
    }
  };

  const int arow = (wr << 7) + fr;
  const int brow = (wc << 6) + fr;

  auto ldA = [&](int i8, int kk, int bufSel) -> bf16x8 {
    const int row = arow + (i8 << 4);
    const int cb = ((kk << 2) | fg) ^ (row & 7);
    return *(const bf16x8*)(lds + (bufSel << 16) + row * 128 + (cb << 4));
  };
  auto ldB = [&](int j, int kk, int bufSel) -> bf16x8 {
    const int row = brow + (j << 4);
    const int cb = ((kk << 2) | fg) ^ (row & 7);
    return *(const bf16x8*)(lds + (bufSel << 16) + 32768 + row * 128 + (cb << 4));
  };

  f32x4 acc[8][4];
#pragma unroll
  for (int i = 0; i < 8; ++i)
#pragma unroll
    for (int j = 0; j < 4; ++j) acc[i][j] = f32x4{0.f, 0.f, 0.f, 0.f};

  // prologue: buf0 fully (kt=0), buf1 units 0-2 (kt=1). 14 gloads in flight.
  stage(0, 0, 0); stage(0, 1, 0); stage(0, 2, 0); stage(0, 3, 0);
  stage(1, 0, 1); stage(1, 1, 1); stage(1, 2, 1);
  VM(6);        // oldest 8 (all of buf0) landed; buf1's 6 stay in flight
  SBAR();

  bf16x8 fa[4][2], fb[4][2];

#define MFMA_Q(QI, QJ)                                                        \
  __builtin_amdgcn_s_setprio(1);                                             \
  _Pragma("unroll") for (int i = 0; i < 4; ++i)                               \
  _Pragma("unroll") for (int j = 0; j < 2; ++j)                               \
  _Pragma("unroll") for (int kk = 0; kk < 2; ++kk)                            \
    acc[(QI)*4 + i][(QJ)*2 + j] = __builtin_amdgcn_mfma_f32_16x16x32_bf16(    \
        fa[i][kk], fb[(QJ)*2 + j][kk], acc[(QI)*4 + i][(QJ)*2 + j], 0, 0, 0); \
  __builtin_amdgcn_s_setprio(0);

#pragma unroll 1
  for (int it = 0; it < NT; ++it) {
    const int kt1 = 2 * it + 1;
    const int ktn0 = 2 * it + 2;   // next tiles (wrapped in stage())
    const int ktn1 = 2 * it + 3;
    // ---- phase 0 (buf0, quadrant 0,0)
#pragma unroll
    for (int i = 0; i < 4; ++i) { fa[i][0] = ldA(i, 0, 0); fa[i][1] = ldA(i, 1, 0); }
#pragma unroll
    for (int j = 0; j < 2; ++j) { fb[j][0] = ldB(j, 0, 0); fb[j][1] = ldB(j, 1, 0); }
    stage(1, 3, kt1);
    SBAR(); LGKM0();
    MFMA_Q(0, 0);
    SBAR();
    // ---- phase 1 (buf0, quadrant 0,1)
#pragma unroll
    for (int j = 2; j < 4; ++j) { fb[j][0] = ldB(j, 0, 0); fb[j][1] = ldB(j, 1, 0); }
    stage(0, 0, ktn0);
    SBAR(); LGKM0();
    MFMA_Q(0, 1);
    SBAR();
    // ---- phase 2 (buf0, quadrant 1,0)
#pragma unroll
    for (int i = 0; i < 4; ++i) { fa[i][0] = ldA(4 + i, 0, 0); fa[i][1] = ldA(4 + i, 1, 0); }
    stage(0, 1, ktn0);
    SBAR(); LGKM0();
    MFMA_Q(1, 0);
    SBAR();
    // ---- phase 3 (buf0, quadrant 1,1)
    stage(0, 2, ktn0);
    SBAR(); LGKM0();
    MFMA_Q(1, 1);
    VM(6);       // buf1 (kt1) fully landed before phase 4
    SBAR();
    // ---- phase 4 (buf1, quadrant 0,0)
#pragma unroll
    for (int i = 0; i < 4; ++i) { fa[i][0] = ldA(i, 0, 1); fa[i][1] = ldA(i, 1, 1); }
#pragma unroll
    for (int j = 0; j < 2; ++j) { fb[j][0] = ldB(j, 0, 1); fb[j][1] = ldB(j, 1, 1); }
    stage(0, 3, ktn0);
    SBAR(); LGKM0();
    MFMA_Q(0, 0);
    SBAR();
    // ---- phase 5 (buf1, quadrant 0,1)
#pragma unroll
    for (int j = 2; j < 4; ++j) { fb[j][0] = ldB(j, 0, 1); fb[j][1] = ldB(j, 1, 1); }
    stage(1, 0, ktn1);
    SBAR(); LGKM0();
    MFMA_Q(0, 1);
    SBAR();
    // ---- phase 6 (buf1, quadrant 1,0)
#pragma unroll
    for (int i = 0; i < 4; ++i) { fa[i][0] = ldA(4 + i, 0, 1); fa[i][1] = ldA(4 + i, 1, 1); }
    stage(1, 1, ktn1);
    SBAR(); LGKM0();
    MFMA_Q(1, 0);
    SBAR();
    // ---- phase 7 (buf1, quadrant 1,1)
    stage(1, 2, ktn1);
    SBAR(); LGKM0();
    MFMA_Q(1, 1);
    VM(6);       // buf0 (ktn0) fully landed before next phase 0
    SBAR();
  }
  VM(0);  // drain wrapped prefetches: no stale LDS writes into successor block
  SBAR();

  // epilogue: D row=(lane>>4)*4+r, col=lane&15 within each 16x16 fragment
#pragma unroll
  for (int ii = 0; ii < 8; ++ii)
#pragma unroll
    for (int j = 0; j < 4; ++j)
#pragma unroll
      for (int r = 0; r < 4; ++r) {
        const int row = Mbase + (wr << 7) + ii * 16 + fg * 4 + r;
        const int col = Nbase + (wc << 6) + j * 16 + fr;
        float val = acc[ii][j][r];
        const long off = (long)z * g.cBatch + (long)row * LDC + col;
        if (EPI == EPI_QK) {
          val = (col < 1024) ? (val + g.bias[col]) * 0.03125f
                             : (val + g.bias2[col - 1024]);
          ((unsigned short*)g.C)[off] = f2bf(val);
        } else if (EPI == EPI_V) {
          val += g.bias[row];
          ((unsigned short*)g.C)[off] = f2bf(val);
        } else if (EPI == EPI_S) {
          ((float*)g.C)[off] = val;
        } else if (EPI == EPI_PV) {
          val = fmaxf(val, 0.f);
          ((unsigned short*)g.C)[off] = f2bf(val);
        } else {  // EPI_OUT
          val = (val + g.bias[row]) * g.mask[col];
          ((float*)g.C)[off] = val;
        }
      }
#undef MFMA_Q
}

// ------------------------------------------------------------------- softmax
__global__ __launch_bounds__(256) void softmax_k(const float* __restrict__ S,
                                                 const float* __restrict__ mask,
                                                 unsigned short* __restrict__ P) {
  const int row = blockIdx.x;      // n*512 + l
  const int n = row >> 9;
  const float* s = S + (long)row * 1024;
  unsigned short* p = P + (long)row * 1024;
  const int t = threadIdx.x;

  float logit[4], fm[4];
  float lmax = -3.0e38f;
#pragma unroll
  for (int i = 0; i < 4; ++i) {
    int m = i * 256 + t;
    int pos = (n << 9) + m - 256;
    float f = (((unsigned)pos < 16384u) && (m != 1023)) ? mask[pos] : 0.f;
    float lg = s[m] + logf(f + 1e-9f);
    fm[i] = f; logit[i] = lg;
    lmax = fmaxf(lmax, lg);
  }
#pragma unroll
  for (int o = 32; o; o >>= 1) lmax = fmaxf(lmax, __shfl_xor(lmax, o, 64));
  __shared__ float red[8];
  const int wv_ = t >> 6, ln = t & 63;
  if (ln == 0) red[wv_] = lmax;
  __syncthreads();
  const float gmax = fmaxf(fmaxf(red[0], red[1]), fmaxf(red[2], red[3]));

  float e[4], lsum = 0.f;
#pragma unroll
  for (int i = 0; i < 4; ++i) { e[i] = expf(logit[i] - gmax); lsum += e[i]; }
#pragma unroll
  for (int o = 32; o; o >>= 1) lsum += __shfl_xor(lsum, o, 64);
  __syncthreads();
  if (ln == 0) red[4 + wv_] = lsum;
  __syncthreads();
  const float inv = 1.f / ((red[4] + red[5]) + (red[6] + red[7]));
#pragma unroll
  for (int i = 0; i < 4; ++i) {
    int m = i * 256 + t;
    p[m] = f2bf(e[i] * inv * fm[i]);
  }
}

// -------------------------------------------------------------------- launch
extern "C" void kernel_launch(void* const* d_in, const int* in_sizes, int n_in,
                              void* d_out, int out_size, void* d_ws, size_t ws_size,
                              hipStream_t stream) {
  const float* x1 = (const float*)d_in[0];
  const float* mask = (const float*)d_in[2];
  const float* wq = (const float*)d_in[3];
  const float* bq = (const float*)d_in[4];
  const float* wk = (const float*)d_in[5];
  const float* bk = (const float*)d_in[6];
  const float* wv = (const float*)d_in[7];
  const float* bv = (const float*)d_in[8];
  const float* wo = (const float*)d_in[9];
  const float* bo = (const float*)d_in[10];

  char* ws = (char*)d_ws;
  unsigned short* xT   = (unsigned short*)(ws);                  // 64 MiB
  unsigned short* attT = xT;                                     // alias
  unsigned short* Wqk  = (unsigned short*)(ws + 67108864);       // 8 MiB
  unsigned short* Wv   = (unsigned short*)(ws + 75497472);       // 4 MiB
  unsigned short* Wo   = (unsigned short*)(ws + 79691776);       // 4 MiB
  unsigned short* qkT  = (unsigned short*)(ws + 83886080);       // 64 MiB
  unsigned short* vbuf = (unsigned short*)(ws + 150994944);      // 32 MiB
  float*          Sbuf = (float*)(ws + 184549376);               // 64 MiB
  unsigned short* P    = (unsigned short*)(ws + 251658240);      // 32 MiB
  unsigned short* guard= (unsigned short*)(ws + 285212672);      // 4 KiB zeros

  hipMemsetAsync(guard, 0, 4096, stream);

  transpose_x_k<<<dim3(512, 64), dim3(32, 8), 0, stream>>>(x1, xT);
  conv_w_k<<<dim3(32768), dim3(256), 0, stream>>>(wq, wk, wv, wo, Wqk, Wv, Wo);

  const int BIG = 0x40000000;
  // 1) qkT[16384][2048] = xT @ Wqk^T (+bias, q-part scaled 1/32)
  {
    GArgs a{};
    a.A = xT; a.Bt = Wqk; a.C = qkT;
    a.bias = bq; a.bias2 = bk; a.guard = guard;
    a.aBatch = 0; a.cBatch = 0;
    a.btRow0 = 0; a.btRow0Step = 0; a.btRowLim = BIG;
    a.btK0 = 0; a.btK0Step = 0; a.btKLim = BIG;
    gemm8_k<EPI_QK, 2048, 2048, 2048, 2048><<<dim3(8, 64, 1), 512, 0, stream>>>(a);
  }
  // 2) v[1024][16384] = Wv @ x (+bv)
  {
    GArgs a{};
    a.A = Wv; a.Bt = xT; a.C = vbuf;
    a.bias = bv; a.guard = guard;
    a.aBatch = 0; a.cBatch = 0;
    a.btRow0 = 0; a.btRow0Step = 0; a.btRowLim = BIG;
    a.btK0 = 0; a.btK0Step = 0; a.btKLim = BIG;
    gemm8_k<EPI_V, 2048, 2048, 16384, 2048><<<dim3(64, 4, 1), 512, 0, stream>>>(a);
  }
  // 3) S[n][512][1024] = Qb @ Kb^T (halo rows via guard)
  {
    GArgs a{};
    a.A = qkT; a.Bt = qkT; a.C = Sbuf;
    a.guard = guard;
    a.aBatch = 512 * 2048; a.cBatch = 512 * 1024;
    a.btRow0 = -256; a.btRow0Step = 512; a.btRowLim = 16384;
    a.btK0 = 1024; a.btK0Step = 0; a.btKLim = BIG;
    gemm8_k<EPI_S, 2048, 2048, 1024, 1024><<<dim3(4, 2, 32), 512, 0, stream>>>(a);
  }
  // 4) softmax rows -> P bf16
  softmax_k<<<dim3(16384), dim3(256), 0, stream>>>(Sbuf, mask, P);
  // 5) attT[n][512][1024] = relu(P @ Vb^T) (halo cols via guard)
  {
    GArgs a{};
    a.A = P; a.Bt = vbuf; a.C = attT;
    a.guard = guard;
    a.aBatch = 512 * 1024; a.cBatch = 512 * 1024;
    a.btRow0 = 0; a.btRow0Step = 0; a.btRowLim = BIG;
    a.btK0 = -256; a.btK0Step = 512; a.btKLim = 16384;
    gemm8_k<EPI_PV, 1024, 16384, 1024, 1024><<<dim3(4, 2, 32), 512, 0, stream>>>(a);
  }
  // 6) out[2048][16384] = (Wo @ attT^T + bo) * mask (fp32)
  {
    GArgs a{};
    a.A = Wo; a.Bt = attT; a.C = d_out;
    a.bias = bo; a.mask = mask; a.guard = guard;
    a.aBatch = 0; a.cBatch = 0;
    a.btRow0 = 0; a.btRow0Step = 0; a.btRowLim = BIG;
    a.btK0 = 0; a.btK0Step = 0; a.btKLim = BIG;
    gemm8_k<EPI_OUT, 1024, 1024, 16384, 1024><<<dim3(64, 8, 1), 512, 0, stream>>>(a);
  }
  (void)in_sizes; (void)n_in; (void)out_size; (void)ws_size;
}